// Round 7
// baseline (584.668 us; speedup 1.0000x reference)
//
#include <hip/hip_runtime.h>

#define HID 256
#define IN_CH 512
#define NPAD 50176

typedef __attribute__((ext_vector_type(8))) short s16x8;
typedef __attribute__((ext_vector_type(4))) float f32x4;
typedef __attribute__((ext_vector_type(4))) _Float16 f16x4;

#define GLBP(p) ((const __attribute__((address_space(1))) void*)(p))
#define LDSP(p) ((__attribute__((address_space(3))) void*)(p))

// ---------------- CSR build ----------------

__global__ __launch_bounds__(256) void k_count(const int* __restrict__ dst,
                                               int* __restrict__ cnt, int E) {
    int e = blockIdx.x * 256 + threadIdx.x;
    if (e < E) atomicAdd(&cnt[dst[e]], 1);
}

__global__ __launch_bounds__(256) void k_scan_bsum(const int* __restrict__ cnt,
                                                   int* __restrict__ bsum, int n) {
    __shared__ int sdata[256];
    int t = threadIdx.x;
    int base = blockIdx.x * 1024 + t * 4;
    int s = 0;
#pragma unroll
    for (int j = 0; j < 4; ++j) if (base + j < n) s += cnt[base + j];
    sdata[t] = s;
    __syncthreads();
    for (int off = 128; off > 0; off >>= 1) {
        if (t < off) sdata[t] += sdata[t + off];
        __syncthreads();
    }
    if (t == 0) bsum[blockIdx.x] = sdata[0];
}

__global__ __launch_bounds__(64) void k_scan_boff(const int* __restrict__ bsum,
                                                  int* __restrict__ boff, int nb) {
    int lane = threadIdx.x;
    int own = (lane < nb) ? bsum[lane] : 0;
    int v = own;
    for (int off = 1; off < 64; off <<= 1) {
        int u = __shfl_up(v, off, 64);
        if (lane >= off) v += u;
    }
    if (lane < nb) boff[lane] = v - own;
}

// pass 3: rowptr (+1-indexed inclusive prefix) AND dinv in one pass
__global__ __launch_bounds__(256) void k_scan_write(const int* __restrict__ cnt,
                                                    const int* __restrict__ boff,
                                                    int* __restrict__ rowptr,
                                                    float* __restrict__ dinv, int n) {
    __shared__ int sdata[256];
    int t = threadIdx.x;
    int base = blockIdx.x * 1024 + t * 4;
    int c0 = (base + 0 < n) ? cnt[base + 0] : 0;
    int c1 = (base + 1 < n) ? cnt[base + 1] : 0;
    int c2 = (base + 2 < n) ? cnt[base + 2] : 0;
    int c3 = (base + 3 < n) ? cnt[base + 3] : 0;
    int tsum = c0 + c1 + c2 + c3;
    sdata[t] = tsum;
    __syncthreads();
    for (int off = 1; off < 256; off <<= 1) {
        int v = (t >= off) ? sdata[t - off] : 0;
        __syncthreads();
        if (t >= off) sdata[t] += v;
        __syncthreads();
    }
    int excl = sdata[t] - tsum;
    int p = boff[blockIdx.x] + excl;
    if (base + 0 < n) { rowptr[base + 1] = p + c0;                dinv[base + 0] = rsqrtf((float)(c0 + 1)); }
    if (base + 1 < n) { rowptr[base + 2] = p + c0 + c1;           dinv[base + 1] = rsqrtf((float)(c1 + 1)); }
    if (base + 2 < n) { rowptr[base + 3] = p + c0 + c1 + c2;      dinv[base + 2] = rsqrtf((float)(c2 + 1)); }
    if (base + 3 < n) { rowptr[base + 4] = p + c0 + c1 + c2 + c3; dinv[base + 3] = rsqrtf((float)(c3 + 1)); }
    if (blockIdx.x == 0 && t == 0) rowptr[0] = 0;
}

// fill sorted edge records {src, norm}
__global__ __launch_bounds__(256) void k_fill(const int* __restrict__ src,
                                              const int* __restrict__ dst,
                                              const int* __restrict__ rowptr,
                                              int* __restrict__ cursor,
                                              const float* __restrict__ dinv,
                                              int2* __restrict__ erec, int E) {
    int e = blockIdx.x * 256 + threadIdx.x;
    if (e >= E) return;
    int d = dst[e];
    int s = src[e];
    int pos = rowptr[d] + atomicAdd(&cursor[d], 1);
    float w = dinv[s] * dinv[d];
    erec[pos] = make_int2(s, __float_as_int(w));
}

// ---------------- weight pre-split (all 3 weights, one launch) ----------------
// W[K][256] fp32 -> Bt'[K/32][256][104] bf16, triplet {hi,hi,lo} per orig k.

__device__ __forceinline__ void wsplit_one(const float* W, unsigned short* Bt, int idx) {
    int n = idx & 255;
    int k = idx >> 8;
    float w = W[(size_t)k * HID + n];
    unsigned int u = __float_as_uint(w);
    unsigned short hi = (unsigned short)(u >> 16);
    float hif = __uint_as_float(u & 0xffff0000u);
    float lo = w - hif;
    unsigned short lob = (unsigned short)(__float_as_uint(lo) >> 16);
    unsigned short* p = Bt + (size_t)(k >> 5) * (HID * 104) + n * 104 + 3 * (k & 31);
    p[0] = hi; p[1] = hi; p[2] = lob;
}

__global__ __launch_bounds__(256) void k_wsplit3(const float* __restrict__ W0,
                                                 const float* __restrict__ W1,
                                                 const float* __restrict__ W2,
                                                 unsigned short* __restrict__ Bt0,
                                                 unsigned short* __restrict__ Bt1,
                                                 unsigned short* __restrict__ Bt2) {
    int t = blockIdx.x * 256 + threadIdx.x;
    if (t < IN_CH * HID) wsplit_one(W0, Bt0, t);
    else if (t < IN_CH * HID + HID * HID) wsplit_one(W1, Bt1, t - IN_CH * HID);
    else wsplit_one(W2, Bt2, t - IN_CH * HID - HID * HID);
}

// ---------------- MFMA GEMM: C16[M,256] = act(A)[M,K] @ W[K,256], fp16 out ----------------
// BM=128, BN=128 (grid.y=2), BK_orig=32 (eff 96). 512 thr = 8 waves (2m x 4n),
// wave tile 64x32 -> acc[4][2]. LDS 53 KB -> 3 blocks/CU.

template<bool RELU>
__global__ __launch_bounds__(512, 6) void k_gemm_mfma(const float* __restrict__ A,
                                                      const unsigned short* __restrict__ Bt,
                                                      _Float16* __restrict__ C16,
                                                      int M, int Korig) {
    __shared__ unsigned short Als[128 * 104];  // 26,624 B
    __shared__ unsigned short Bls[128 * 104];  // 26,624 B  ([n-local][k_eff])

    const int m0 = blockIdx.x * 128;
    const int n0 = blockIdx.y * 128;
    const int tid = threadIdx.x;
    const int wave = tid >> 6;
    const int lane = tid & 63;
    const int wm = wave >> 2;      // 0..1
    const int wn = wave & 3;       // 0..3

    f32x4 acc[4][2] = {};

    const int nsteps = Korig >> 5;
    const int arow = tid >> 2;
    const int aseg = (tid & 3) * 8;

    for (int ks = 0; ks < nsteps; ++ks) {
        // ---- stage A: load 8 fp32, split, interleave {hi,lo,hi}, 3x ds_write_b128
        {
            int gm = m0 + arow;
            float4 v0 = make_float4(0, 0, 0, 0), v1 = v0;
            if (gm < M) {
                const float* ap = A + (size_t)gm * Korig + ks * 32 + aseg;
                v0 = *(const float4*)ap;
                v1 = *(const float4*)(ap + 4);
            }
            float av[8] = {v0.x, v0.y, v0.z, v0.w, v1.x, v1.y, v1.z, v1.w};
            unsigned short hi[8], lo[8];
#pragma unroll
            for (int j = 0; j < 8; ++j) {
                float a = av[j];
                if (RELU) a = fmaxf(a, 0.f);
                unsigned int u = __float_as_uint(a);
                hi[j] = (unsigned short)(u >> 16);
                float hif = __uint_as_float(u & 0xffff0000u);
                float l = a - hif;
                lo[j] = (unsigned short)(__float_as_uint(l) >> 16);
            }
            s16x8 w0 = {(short)hi[0], (short)lo[0], (short)hi[0], (short)hi[1],
                        (short)lo[1], (short)hi[1], (short)hi[2], (short)lo[2]};
            s16x8 w1 = {(short)hi[2], (short)hi[3], (short)lo[3], (short)hi[3],
                        (short)hi[4], (short)lo[4], (short)hi[4], (short)hi[5]};
            s16x8 w2 = {(short)lo[5], (short)hi[5], (short)hi[6], (short)lo[6],
                        (short)hi[6], (short)hi[7], (short)lo[7], (short)hi[7]};
            s16x8* dp = (s16x8*)&Als[arow * 104 + (tid & 3) * 24];
            dp[0] = w0; dp[1] = w1; dp[2] = w2;
        }
        // ---- stage B' half-tile: 26,624 B = 1664 x 16B = 26 wave-groups
        {
            const char* src = (const char*)(Bt + (size_t)ks * (HID * 104) + (size_t)n0 * 104);
            for (int g = wave; g < 26; g += 8) {
                int byteoff = (g * 64 + lane) * 16;
                __builtin_amdgcn_global_load_lds(GLBP(src + byteoff),
                                                 LDSP((char*)Bls + byteoff), 16, 0, 0);
            }
        }
        __syncthreads();

#pragma unroll
        for (int kk = 0; kk < 3; ++kk) {
            int gsh = (kk * 4 + (lane >> 4)) * 8;
            s16x8 af[4], bf[2];
#pragma unroll
            for (int mf = 0; mf < 4; ++mf) {
                int row = wm * 64 + mf * 16 + (lane & 15);
                af[mf] = *(const s16x8*)&Als[row * 104 + gsh];
            }
#pragma unroll
            for (int nf = 0; nf < 2; ++nf) {
                int col = wn * 32 + nf * 16 + (lane & 15);
                bf[nf] = *(const s16x8*)&Bls[col * 104 + gsh];
            }
#pragma unroll
            for (int mf = 0; mf < 4; ++mf)
#pragma unroll
                for (int nf = 0; nf < 2; ++nf)
                    acc[mf][nf] = __builtin_amdgcn_mfma_f32_16x16x32_bf16(af[mf], bf[nf],
                                                                          acc[mf][nf], 0, 0, 0);
        }
        __syncthreads();
    }

    // ---- epilogue: C/D layout col=lane&15, row=(lane>>4)*4+r
#pragma unroll
    for (int mf = 0; mf < 4; ++mf) {
        int row0 = m0 + wm * 64 + mf * 16 + (lane >> 4) * 4;
#pragma unroll
        for (int r = 0; r < 4; ++r) {
            int gr = row0 + r;
            if (gr < M) {
#pragma unroll
                for (int nf = 0; nf < 2; ++nf) {
                    int col = n0 + wn * 32 + nf * 16 + (lane & 15);
                    C16[(size_t)gr * HID + col] = (_Float16)acc[mf][nf][r];
                }
            }
        }
    }
}

// ---------------- gather aggregate: one wave per dst node, fp16 h, fp32 acc ----------------

template<bool READOUT>
__global__ __launch_bounds__(256) void k_aggregate(const _Float16* __restrict__ h,
                                                   const float* __restrict__ dinv,
                                                   const int* __restrict__ rowptr,
                                                   const int2* __restrict__ erec,
                                                   const float* __restrict__ bias,
                                                   float* __restrict__ agg,
                                                   const float* __restrict__ wout,
                                                   const float* __restrict__ bout,
                                                   float* __restrict__ out,
                                                   int n) {
    int node = blockIdx.x * 4 + (threadIdx.x >> 6);
    if (node >= n) return;
    int lane = threadIdx.x & 63;

    float dd = dinv[node];
    float4 acc;
    {
        float w = dd * dd;
        f16x4 v = *(const f16x4*)(h + (size_t)node * HID + lane * 4);
        float4 b = *(const float4*)(bias + lane * 4);
        acc = make_float4(b.x + (float)v[0] * w, b.y + (float)v[1] * w,
                          b.z + (float)v[2] * w, b.w + (float)v[3] * w);
    }

    int e = rowptr[node];
    int e_end = rowptr[node + 1];
    for (; e + 1 < e_end; e += 2) {
        int2 r0 = erec[e];
        int2 r1 = erec[e + 1];
        float w0 = __int_as_float(r0.y);
        float w1 = __int_as_float(r1.y);
        f16x4 v0 = *(const f16x4*)(h + (size_t)r0.x * HID + lane * 4);
        f16x4 v1 = *(const f16x4*)(h + (size_t)r1.x * HID + lane * 4);
        acc.x += (float)v0[0] * w0 + (float)v1[0] * w1;
        acc.y += (float)v0[1] * w0 + (float)v1[1] * w1;
        acc.z += (float)v0[2] * w0 + (float)v1[2] * w1;
        acc.w += (float)v0[3] * w0 + (float)v1[3] * w1;
    }
    if (e < e_end) {
        int2 r0 = erec[e];
        float w0 = __int_as_float(r0.y);
        f16x4 v0 = *(const f16x4*)(h + (size_t)r0.x * HID + lane * 4);
        acc.x += (float)v0[0] * w0; acc.y += (float)v0[1] * w0;
        acc.z += (float)v0[2] * w0; acc.w += (float)v0[3] * w0;
    }

    if (!READOUT) {
        *(float4*)(agg + (size_t)node * HID + lane * 4) = acc;
    } else {
        float4 w = *(const float4*)(wout + lane * 4);
        acc.x = fmaxf(acc.x, 0.f); acc.y = fmaxf(acc.y, 0.f);
        acc.z = fmaxf(acc.z, 0.f); acc.w = fmaxf(acc.w, 0.f);
        float s = acc.x * w.x + acc.y * w.y + acc.z * w.z + acc.w * w.w;
#pragma unroll
        for (int off = 32; off > 0; off >>= 1) s += __shfl_down(s, off, 64);
        if (lane == 0) out[node] = s + bout[0];
    }
}

// ---------------- launch ----------------

extern "C" void kernel_launch(void* const* d_in, const int* in_sizes, int n_in,
                              void* d_out, int out_size, void* d_ws, size_t ws_size,
                              hipStream_t stream) {
    const float* x    = (const float*)d_in[0];
    const int*   ei   = (const int*)d_in[1];
    const float* W0   = (const float*)d_in[2];
    const float* b0   = (const float*)d_in[3];
    const float* W1   = (const float*)d_in[4];
    const float* b1   = (const float*)d_in[5];
    const float* W2   = (const float*)d_in[6];
    const float* b2   = (const float*)d_in[7];
    const float* Wout = (const float*)d_in[8];
    const float* bout = (const float*)d_in[9];
    float* out = (float*)d_out;

    const int n = in_sizes[0] / IN_CH;   // 50000
    const int E = in_sizes[1] / 2;       // 800000
    const int* src = ei;
    const int* dst = ei + E;

    // workspace carve-up
    float* dinv   = (float*)d_ws;                        // NPAD
    int*   rowptr = (int*)(dinv + NPAD);                 // NPAD
    int*   cursor = rowptr + NPAD;                       // NPAD
    int2*  erec   = (int2*)(cursor + NPAD);              // E (8B each)
    int*   bsum   = (int*)(erec + 800000);               // 64
    int*   boff   = bsum + 64;                           // 64
    unsigned short* Bt0 = (unsigned short*)(boff + 64);  // 16*256*104
    unsigned short* Bt1 = Bt0 + 16 * HID * 104;          // 8*256*104
    unsigned short* Bt2 = Bt1 + 8 * HID * 104;           // 8*256*104
    _Float16* h16 = (_Float16*)(Bt2 + 8 * HID * 104);    // n*HID fp16
    float* agg32  = (float*)(h16 + (size_t)n * HID);     // n*HID fp32

    const int nb_e = (E + 255) / 256;
    const int nb_scan = (n + 1023) / 1024;

    // ---- CSR build ----
    hipMemsetAsync(cursor, 0, (size_t)n * 4, stream);
    k_count<<<nb_e, 256, 0, stream>>>(dst, cursor, E);
    k_scan_bsum<<<nb_scan, 256, 0, stream>>>(cursor, bsum, n);
    k_scan_boff<<<1, 64, 0, stream>>>(bsum, boff, nb_scan);
    k_scan_write<<<nb_scan, 256, 0, stream>>>(cursor, boff, rowptr, dinv, n);
    hipMemsetAsync(cursor, 0, (size_t)n * 4, stream);
    k_fill<<<nb_e, 256, 0, stream>>>(src, dst, rowptr, cursor, dinv, erec, E);

    // ---- weight pre-split (one launch) ----
    k_wsplit3<<<(IN_CH * HID + 2 * HID * HID) / 256, 256, 0, stream>>>(W0, W1, W2, Bt0, Bt1, Bt2);

    dim3 gg((n + 127) / 128, 2);
    const int agg_blocks = (n + 3) / 4;

    // layer 0
    k_gemm_mfma<false><<<gg, 512, 0, stream>>>(x, Bt0, h16, n, IN_CH);
    k_aggregate<false><<<agg_blocks, 256, 0, stream>>>(h16, dinv, rowptr, erec, b0,
                                                       agg32, nullptr, nullptr, nullptr, n);
    // layer 1
    k_gemm_mfma<true><<<gg, 512, 0, stream>>>(agg32, Bt1, h16, n, HID);
    k_aggregate<false><<<agg_blocks, 256, 0, stream>>>(h16, dinv, rowptr, erec, b1,
                                                       agg32, nullptr, nullptr, nullptr, n);
    // layer 2 + fused readout
    k_gemm_mfma<true><<<gg, 512, 0, stream>>>(agg32, Bt2, h16, n, HID);
    k_aggregate<true><<<agg_blocks, 256, 0, stream>>>(h16, dinv, rowptr, erec, b2,
                                                      nullptr, Wout, bout, out, n);
}

// Round 8
// 545.934 us; speedup vs baseline: 1.0709x; 1.0709x over previous
//
#include <hip/hip_runtime.h>

#define HID 256
#define IN_CH 512
#define NPAD 50176

// granule-major GEMM tile geometry: K-step = 32 orig k -> 96 eff shorts = 12 granules of 16 B
#define NGRAN 12
#define BTSTEP (NGRAN * 256 * 8)   // shorts per K-step tile of B' (49,152 B)

typedef __attribute__((ext_vector_type(8))) short s16x8;
typedef __attribute__((ext_vector_type(4))) float f32x4;
typedef __attribute__((ext_vector_type(4))) _Float16 f16x4;

#define GLBP(p) ((const __attribute__((address_space(1))) void*)(p))
#define LDSP(p) ((__attribute__((address_space(3))) void*)(p))

// ---------------- CSR build ----------------

__global__ __launch_bounds__(256) void k_count(const int* __restrict__ dst,
                                               int* __restrict__ cnt, int E) {
    int e = blockIdx.x * 256 + threadIdx.x;
    if (e < E) atomicAdd(&cnt[dst[e]], 1);
}

__global__ __launch_bounds__(256) void k_scan_bsum(const int* __restrict__ cnt,
                                                   int* __restrict__ bsum, int n) {
    __shared__ int sdata[256];
    int t = threadIdx.x;
    int base = blockIdx.x * 1024 + t * 4;
    int s = 0;
#pragma unroll
    for (int j = 0; j < 4; ++j) if (base + j < n) s += cnt[base + j];
    sdata[t] = s;
    __syncthreads();
    for (int off = 128; off > 0; off >>= 1) {
        if (t < off) sdata[t] += sdata[t + off];
        __syncthreads();
    }
    if (t == 0) bsum[blockIdx.x] = sdata[0];
}

__global__ __launch_bounds__(64) void k_scan_boff(const int* __restrict__ bsum,
                                                  int* __restrict__ boff, int nb) {
    int lane = threadIdx.x;
    int own = (lane < nb) ? bsum[lane] : 0;
    int v = own;
    for (int off = 1; off < 64; off <<= 1) {
        int u = __shfl_up(v, off, 64);
        if (lane >= off) v += u;
    }
    if (lane < nb) boff[lane] = v - own;
}

// pass 3: rowptr AND dinv in one pass
__global__ __launch_bounds__(256) void k_scan_write(const int* __restrict__ cnt,
                                                    const int* __restrict__ boff,
                                                    int* __restrict__ rowptr,
                                                    float* __restrict__ dinv, int n) {
    __shared__ int sdata[256];
    int t = threadIdx.x;
    int base = blockIdx.x * 1024 + t * 4;
    int c0 = (base + 0 < n) ? cnt[base + 0] : 0;
    int c1 = (base + 1 < n) ? cnt[base + 1] : 0;
    int c2 = (base + 2 < n) ? cnt[base + 2] : 0;
    int c3 = (base + 3 < n) ? cnt[base + 3] : 0;
    int tsum = c0 + c1 + c2 + c3;
    sdata[t] = tsum;
    __syncthreads();
    for (int off = 1; off < 256; off <<= 1) {
        int v = (t >= off) ? sdata[t - off] : 0;
        __syncthreads();
        if (t >= off) sdata[t] += v;
        __syncthreads();
    }
    int excl = sdata[t] - tsum;
    int p = boff[blockIdx.x] + excl;
    if (base + 0 < n) { rowptr[base + 1] = p + c0;                dinv[base + 0] = rsqrtf((float)(c0 + 1)); }
    if (base + 1 < n) { rowptr[base + 2] = p + c0 + c1;           dinv[base + 1] = rsqrtf((float)(c1 + 1)); }
    if (base + 2 < n) { rowptr[base + 3] = p + c0 + c1 + c2;      dinv[base + 2] = rsqrtf((float)(c2 + 1)); }
    if (base + 3 < n) { rowptr[base + 4] = p + c0 + c1 + c2 + c3; dinv[base + 3] = rsqrtf((float)(c3 + 1)); }
    if (blockIdx.x == 0 && t == 0) rowptr[0] = 0;
}

// fill sorted edge records {src, norm}
__global__ __launch_bounds__(256) void k_fill(const int* __restrict__ src,
                                              const int* __restrict__ dst,
                                              const int* __restrict__ rowptr,
                                              int* __restrict__ cursor,
                                              const float* __restrict__ dinv,
                                              int2* __restrict__ erec, int E) {
    int e = blockIdx.x * 256 + threadIdx.x;
    if (e >= E) return;
    int d = dst[e];
    int s = src[e];
    int pos = rowptr[d] + atomicAdd(&cursor[d], 1);
    float w = dinv[s] * dinv[d];
    erec[pos] = make_int2(s, __float_as_int(w));
}

// ---------------- weight pre-split (granule-major tiles) ----------------
// W[K][256] fp32 -> per K-step tile [12 granules][256 cols][8 shorts].
// orig k -> eff {3k:hi, 3k+1:hi, 3k+2:lo}.

__device__ __forceinline__ void wsplit_one(const float* W, unsigned short* Bt, int idx) {
    int n = idx & 255;
    int k = idx >> 8;
    float w = W[(size_t)k * HID + n];
    unsigned int u = __float_as_uint(w);
    unsigned short hi = (unsigned short)(u >> 16);
    float hif = __uint_as_float(u & 0xffff0000u);
    float lo = w - hif;
    unsigned short lob = (unsigned short)(__float_as_uint(lo) >> 16);
    unsigned short* base = Bt + (size_t)(k >> 5) * BTSTEP;
    int kz = k & 31;
    int e0 = 3 * kz, e1 = e0 + 1, e2 = e0 + 2;
    base[((e0 >> 3) * 256 + n) * 8 + (e0 & 7)] = hi;
    base[((e1 >> 3) * 256 + n) * 8 + (e1 & 7)] = hi;
    base[((e2 >> 3) * 256 + n) * 8 + (e2 & 7)] = lob;
}

__global__ __launch_bounds__(256) void k_wsplit3(const float* __restrict__ W0,
                                                 const float* __restrict__ W1,
                                                 const float* __restrict__ W2,
                                                 unsigned short* __restrict__ Bt0,
                                                 unsigned short* __restrict__ Bt1,
                                                 unsigned short* __restrict__ Bt2) {
    int t = blockIdx.x * 256 + threadIdx.x;
    if (t < IN_CH * HID) wsplit_one(W0, Bt0, t);
    else if (t < IN_CH * HID + HID * HID) wsplit_one(W1, Bt1, t - IN_CH * HID);
    else wsplit_one(W2, Bt2, t - IN_CH * HID - HID * HID);
}

// ---------------- MFMA GEMM: C16[M,256] = act(A)[M,K] @ W[K,256], fp16 out ----------------
// BM=128, BN=256, BK_orig=32 (eff 96 = 12 granules). 512 thr = 8 waves (2m x 4n),
// wave tile 64x64 -> acc[4][4]. LDS granule-major: conflict-free reads/writes.

template<bool RELU>
__global__ __launch_bounds__(512) void k_gemm_mfma(const float* __restrict__ A,
                                                   const unsigned short* __restrict__ Bt,
                                                   _Float16* __restrict__ C16,
                                                   int M, int Korig) {
    __shared__ s16x8 AlsG[NGRAN * 128];  // 24,576 B, [g][row]
    __shared__ s16x8 BlsG[NGRAN * 256];  // 49,152 B, [g][col]

    const int m0 = blockIdx.x * 128;
    const int tid = threadIdx.x;
    const int wave = tid >> 6;
    const int lane = tid & 63;
    const int wm = wave >> 2;      // 0..1
    const int wn = wave & 3;       // 0..3

    f32x4 acc[4][4] = {};

    const int nsteps = Korig >> 5;
    const int arow = tid >> 2;           // 0..127
    const int at   = tid & 3;            // orig col block of 8

    for (int ks = 0; ks < nsteps; ++ks) {
        // ---- stage A: 8 fp32 -> split -> granules 3t..3t+2 of row arow
        {
            int gm = m0 + arow;
            float4 v0 = make_float4(0, 0, 0, 0), v1 = v0;
            if (gm < M) {
                const float* ap = A + (size_t)gm * Korig + ks * 32 + at * 8;
                v0 = *(const float4*)ap;
                v1 = *(const float4*)(ap + 4);
            }
            float av[8] = {v0.x, v0.y, v0.z, v0.w, v1.x, v1.y, v1.z, v1.w};
            unsigned short hi[8], lo[8];
#pragma unroll
            for (int j = 0; j < 8; ++j) {
                float a = av[j];
                if (RELU) a = fmaxf(a, 0.f);
                unsigned int u = __float_as_uint(a);
                hi[j] = (unsigned short)(u >> 16);
                float hif = __uint_as_float(u & 0xffff0000u);
                float l = a - hif;
                lo[j] = (unsigned short)(__float_as_uint(l) >> 16);
            }
            // eff shorts 24t..24t+23 (granule-aligned since 24t/8 = 3t)
            s16x8 w0 = {(short)hi[0], (short)lo[0], (short)hi[0], (short)hi[1],
                        (short)lo[1], (short)hi[1], (short)hi[2], (short)lo[2]};
            s16x8 w1 = {(short)hi[2], (short)hi[3], (short)lo[3], (short)hi[3],
                        (short)hi[4], (short)lo[4], (short)hi[4], (short)hi[5]};
            s16x8 w2 = {(short)lo[5], (short)hi[5], (short)hi[6], (short)lo[6],
                        (short)hi[6], (short)hi[7], (short)lo[7], (short)hi[7]};
            AlsG[(3 * at + 0) * 128 + arow] = w0;
            AlsG[(3 * at + 1) * 128 + arow] = w1;
            AlsG[(3 * at + 2) * 128 + arow] = w2;
        }
        // ---- stage B': 49,152 B = 3072 x 16B = 48 wave-groups, linear copy
        {
            const char* src = (const char*)(Bt + (size_t)ks * BTSTEP);
            for (int g = wave; g < 48; g += 8) {
                int byteoff = (g * 64 + lane) * 16;
                __builtin_amdgcn_global_load_lds(GLBP(src + byteoff),
                                                 LDSP((char*)BlsG + byteoff), 16, 0, 0);
            }
        }
        __syncthreads();

#pragma unroll
        for (int kk = 0; kk < 3; ++kk) {
            int g = kk * 4 + (lane >> 4);      // granule for this lane-quarter
            s16x8 af[4], bf[4];
#pragma unroll
            for (int mf = 0; mf < 4; ++mf) {
                int row = wm * 64 + mf * 16 + (lane & 15);
                af[mf] = AlsG[g * 128 + row];
            }
#pragma unroll
            for (int nf = 0; nf < 4; ++nf) {
                int col = wn * 64 + nf * 16 + (lane & 15);
                bf[nf] = BlsG[g * 256 + col];
            }
#pragma unroll
            for (int mf = 0; mf < 4; ++mf)
#pragma unroll
                for (int nf = 0; nf < 4; ++nf)
                    acc[mf][nf] = __builtin_amdgcn_mfma_f32_16x16x32_bf16(af[mf], bf[nf],
                                                                          acc[mf][nf], 0, 0, 0);
        }
        __syncthreads();
    }

    // ---- epilogue: C/D layout col=lane&15, row=(lane>>4)*4+r
#pragma unroll
    for (int mf = 0; mf < 4; ++mf) {
        int row0 = m0 + wm * 64 + mf * 16 + (lane >> 4) * 4;
#pragma unroll
        for (int r = 0; r < 4; ++r) {
            int gr = row0 + r;
            if (gr < M) {
#pragma unroll
                for (int nf = 0; nf < 4; ++nf) {
                    int col = wn * 64 + nf * 16 + (lane & 15);
                    C16[(size_t)gr * HID + col] = (_Float16)acc[mf][nf][r];
                }
            }
        }
    }
}

// ---------------- gather aggregate: one wave per dst node, fp16 h, fp32 acc ----------------

template<bool READOUT>
__global__ __launch_bounds__(256) void k_aggregate(const _Float16* __restrict__ h,
                                                   const float* __restrict__ dinv,
                                                   const int* __restrict__ rowptr,
                                                   const int2* __restrict__ erec,
                                                   const float* __restrict__ bias,
                                                   float* __restrict__ agg,
                                                   const float* __restrict__ wout,
                                                   const float* __restrict__ bout,
                                                   float* __restrict__ out,
                                                   int n) {
    int node = blockIdx.x * 4 + (threadIdx.x >> 6);
    if (node >= n) return;
    int lane = threadIdx.x & 63;

    float dd = dinv[node];
    float4 acc;
    {
        float w = dd * dd;
        f16x4 v = *(const f16x4*)(h + (size_t)node * HID + lane * 4);
        float4 b = *(const float4*)(bias + lane * 4);
        acc = make_float4(b.x + (float)v[0] * w, b.y + (float)v[1] * w,
                          b.z + (float)v[2] * w, b.w + (float)v[3] * w);
    }

    int e = rowptr[node];
    int e_end = rowptr[node + 1];
    for (; e + 1 < e_end; e += 2) {
        int2 r0 = erec[e];
        int2 r1 = erec[e + 1];
        float w0 = __int_as_float(r0.y);
        float w1 = __int_as_float(r1.y);
        f16x4 v0 = *(const f16x4*)(h + (size_t)r0.x * HID + lane * 4);
        f16x4 v1 = *(const f16x4*)(h + (size_t)r1.x * HID + lane * 4);
        acc.x += (float)v0[0] * w0 + (float)v1[0] * w1;
        acc.y += (float)v0[1] * w0 + (float)v1[1] * w1;
        acc.z += (float)v0[2] * w0 + (float)v1[2] * w1;
        acc.w += (float)v0[3] * w0 + (float)v1[3] * w1;
    }
    if (e < e_end) {
        int2 r0 = erec[e];
        float w0 = __int_as_float(r0.y);
        f16x4 v0 = *(const f16x4*)(h + (size_t)r0.x * HID + lane * 4);
        acc.x += (float)v0[0] * w0; acc.y += (float)v0[1] * w0;
        acc.z += (float)v0[2] * w0; acc.w += (float)v0[3] * w0;
    }

    if (!READOUT) {
        *(float4*)(agg + (size_t)node * HID + lane * 4) = acc;
    } else {
        float4 w = *(const float4*)(wout + lane * 4);
        acc.x = fmaxf(acc.x, 0.f); acc.y = fmaxf(acc.y, 0.f);
        acc.z = fmaxf(acc.z, 0.f); acc.w = fmaxf(acc.w, 0.f);
        float s = acc.x * w.x + acc.y * w.y + acc.z * w.z + acc.w * w.w;
#pragma unroll
        for (int off = 32; off > 0; off >>= 1) s += __shfl_down(s, off, 64);
        if (lane == 0) out[node] = s + bout[0];
    }
}

// ---------------- launch ----------------

extern "C" void kernel_launch(void* const* d_in, const int* in_sizes, int n_in,
                              void* d_out, int out_size, void* d_ws, size_t ws_size,
                              hipStream_t stream) {
    const float* x    = (const float*)d_in[0];
    const int*   ei   = (const int*)d_in[1];
    const float* W0   = (const float*)d_in[2];
    const float* b0   = (const float*)d_in[3];
    const float* W1   = (const float*)d_in[4];
    const float* b1   = (const float*)d_in[5];
    const float* W2   = (const float*)d_in[6];
    const float* b2   = (const float*)d_in[7];
    const float* Wout = (const float*)d_in[8];
    const float* bout = (const float*)d_in[9];
    float* out = (float*)d_out;

    const int n = in_sizes[0] / IN_CH;   // 50000
    const int E = in_sizes[1] / 2;       // 800000
    const int* src = ei;
    const int* dst = ei + E;

    // workspace carve-up
    float* dinv   = (float*)d_ws;                        // NPAD
    int*   rowptr = (int*)(dinv + NPAD);                 // NPAD
    int*   cursor = rowptr + NPAD;                       // NPAD
    int2*  erec   = (int2*)(cursor + NPAD);              // E (8B each)
    int*   bsum   = (int*)(erec + 800000);               // 64
    int*   boff   = bsum + 64;                           // 64
    unsigned short* Bt0 = (unsigned short*)(boff + 64);  // 16 * BTSTEP
    unsigned short* Bt1 = Bt0 + 16 * BTSTEP;             // 8 * BTSTEP
    unsigned short* Bt2 = Bt1 + 8 * BTSTEP;              // 8 * BTSTEP
    _Float16* h16 = (_Float16*)(Bt2 + 8 * BTSTEP);       // n*HID fp16
    float* agg32  = (float*)(h16 + (size_t)n * HID);     // n*HID fp32

    const int nb_e = (E + 255) / 256;
    const int nb_scan = (n + 1023) / 1024;

    // ---- CSR build ----
    hipMemsetAsync(cursor, 0, (size_t)n * 4, stream);
    k_count<<<nb_e, 256, 0, stream>>>(dst, cursor, E);
    k_scan_bsum<<<nb_scan, 256, 0, stream>>>(cursor, bsum, n);
    k_scan_boff<<<1, 64, 0, stream>>>(bsum, boff, nb_scan);
    k_scan_write<<<nb_scan, 256, 0, stream>>>(cursor, boff, rowptr, dinv, n);
    hipMemsetAsync(cursor, 0, (size_t)n * 4, stream);
    k_fill<<<nb_e, 256, 0, stream>>>(src, dst, rowptr, cursor, dinv, erec, E);

    // ---- weight pre-split (one launch) ----
    k_wsplit3<<<(IN_CH * HID + 2 * HID * HID) / 256, 256, 0, stream>>>(W0, W1, W2, Bt0, Bt1, Bt2);

    const int gemm_blocks = (n + 127) / 128;
    const int agg_blocks = (n + 3) / 4;

    // layer 0
    k_gemm_mfma<false><<<gemm_blocks, 512, 0, stream>>>(x, Bt0, h16, n, IN_CH);
    k_aggregate<false><<<agg_blocks, 256, 0, stream>>>(h16, dinv, rowptr, erec, b0,
                                                       agg32, nullptr, nullptr, nullptr, n);
    // layer 1
    k_gemm_mfma<true><<<gemm_blocks, 512, 0, stream>>>(agg32, Bt1, h16, n, HID);
    k_aggregate<false><<<agg_blocks, 256, 0, stream>>>(h16, dinv, rowptr, erec, b1,
                                                       agg32, nullptr, nullptr, nullptr, n);
    // layer 2 + fused readout
    k_gemm_mfma<true><<<gemm_blocks, 512, 0, stream>>>(agg32, Bt2, h16, n, HID);
    k_aggregate<true><<<agg_blocks, 256, 0, stream>>>(h16, dinv, rowptr, erec, b2,
                                                      nullptr, Wout, bout, out, n);
}

// Round 9
// 506.988 us; speedup vs baseline: 1.1532x; 1.0768x over previous
//
#include <hip/hip_runtime.h>

#define HID 256
#define IN_CH 512
#define NPAD 50176

// fp16 GEMM tile geometry: K-step = 32 k = 4 granules of 8 halves (16 B)
// A tile per step: [4][128][8] halves = 8 KB ; B tile: [4][256][8] = 16 KB
#define A_STEP_SHORTS 4096      // 4*128*8
#define B_STEP_SHORTS 8192      // 4*256*8
#define AGGT_TILE_SHORTS 32768  // 8 ksteps * 4096

typedef __attribute__((ext_vector_type(8))) _Float16 f16x8;
typedef __attribute__((ext_vector_type(4))) _Float16 f16x4;
typedef __attribute__((ext_vector_type(4))) float f32x4;

#define GLBP(p) ((const __attribute__((address_space(1))) void*)(p))
#define LDSP(p) ((__attribute__((address_space(3))) void*)(p))

// ---------------- CSR build ----------------

__global__ __launch_bounds__(256) void k_count(const int* __restrict__ dst,
                                               int* __restrict__ cnt, int E) {
    int e = blockIdx.x * 256 + threadIdx.x;
    if (e < E) atomicAdd(&cnt[dst[e]], 1);
}

__global__ __launch_bounds__(256) void k_scan_bsum(const int* __restrict__ cnt,
                                                   int* __restrict__ bsum, int n) {
    __shared__ int sdata[256];
    int t = threadIdx.x;
    int base = blockIdx.x * 1024 + t * 4;
    int s = 0;
#pragma unroll
    for (int j = 0; j < 4; ++j) if (base + j < n) s += cnt[base + j];
    sdata[t] = s;
    __syncthreads();
    for (int off = 128; off > 0; off >>= 1) {
        if (t < off) sdata[t] += sdata[t + off];
        __syncthreads();
    }
    if (t == 0) bsum[blockIdx.x] = sdata[0];
}

__global__ __launch_bounds__(64) void k_scan_boff(const int* __restrict__ bsum,
                                                  int* __restrict__ boff, int nb) {
    int lane = threadIdx.x;
    int own = (lane < nb) ? bsum[lane] : 0;
    int v = own;
    for (int off = 1; off < 64; off <<= 1) {
        int u = __shfl_up(v, off, 64);
        if (lane >= off) v += u;
    }
    if (lane < nb) boff[lane] = v - own;
}

// pass 3: rowptr AND dinv in one pass
__global__ __launch_bounds__(256) void k_scan_write(const int* __restrict__ cnt,
                                                    const int* __restrict__ boff,
                                                    int* __restrict__ rowptr,
                                                    float* __restrict__ dinv, int n) {
    __shared__ int sdata[256];
    int t = threadIdx.x;
    int base = blockIdx.x * 1024 + t * 4;
    int c0 = (base + 0 < n) ? cnt[base + 0] : 0;
    int c1 = (base + 1 < n) ? cnt[base + 1] : 0;
    int c2 = (base + 2 < n) ? cnt[base + 2] : 0;
    int c3 = (base + 3 < n) ? cnt[base + 3] : 0;
    int tsum = c0 + c1 + c2 + c3;
    sdata[t] = tsum;
    __syncthreads();
    for (int off = 1; off < 256; off <<= 1) {
        int v = (t >= off) ? sdata[t - off] : 0;
        __syncthreads();
        if (t >= off) sdata[t] += v;
        __syncthreads();
    }
    int excl = sdata[t] - tsum;
    int p = boff[blockIdx.x] + excl;
    if (base + 0 < n) { rowptr[base + 1] = p + c0;                dinv[base + 0] = rsqrtf((float)(c0 + 1)); }
    if (base + 1 < n) { rowptr[base + 2] = p + c0 + c1;           dinv[base + 1] = rsqrtf((float)(c1 + 1)); }
    if (base + 2 < n) { rowptr[base + 3] = p + c0 + c1 + c2;      dinv[base + 2] = rsqrtf((float)(c2 + 1)); }
    if (base + 3 < n) { rowptr[base + 4] = p + c0 + c1 + c2 + c3; dinv[base + 3] = rsqrtf((float)(c3 + 1)); }
    if (blockIdx.x == 0 && t == 0) rowptr[0] = 0;
}

// fill sorted edge records {src, norm}
__global__ __launch_bounds__(256) void k_fill(const int* __restrict__ src,
                                              const int* __restrict__ dst,
                                              const int* __restrict__ rowptr,
                                              int* __restrict__ cursor,
                                              const float* __restrict__ dinv,
                                              int2* __restrict__ erec, int E) {
    int e = blockIdx.x * 256 + threadIdx.x;
    if (e >= E) return;
    int d = dst[e];
    int s = src[e];
    int pos = rowptr[d] + atomicAdd(&cursor[d], 1);
    float w = dinv[s] * dinv[d];
    erec[pos] = make_int2(s, __float_as_int(w));
}

// ---------------- weight convert: W[K][256] fp32 -> fp16 granule-major tiles ----------------
// per K-step [4 granules][256 cols][8 halves]; addr = ((ks*4+g)*256+n)*8 + (k&7)

__device__ __forceinline__ void wcvt_one(const float* W, _Float16* Wt, int idx) {
    int n = idx & 255;
    int k = idx >> 8;
    _Float16 v = (_Float16)W[(size_t)k * HID + n];
    int ks = k >> 5, g = (k >> 3) & 3;
    Wt[(((size_t)ks * 4 + g) * 256 + n) * 8 + (k & 7)] = v;
}

__global__ __launch_bounds__(256) void k_wcvt3(const float* __restrict__ W0,
                                               const float* __restrict__ W1,
                                               const float* __restrict__ W2,
                                               _Float16* __restrict__ Wt0,
                                               _Float16* __restrict__ Wt1,
                                               _Float16* __restrict__ Wt2) {
    int t = blockIdx.x * 256 + threadIdx.x;
    if (t < IN_CH * HID) wcvt_one(W0, Wt0, t);
    else if (t < IN_CH * HID + HID * HID) wcvt_one(W1, Wt1, t - IN_CH * HID);
    else wcvt_one(W2, Wt2, t - IN_CH * HID - HID * HID);
}

// ---------------- fp16 MFMA GEMM: C16[M,256] = A[M,K] @ W[K,256] ----------------
// BM=128, BN=256, BK=32. 512 thr = 8 waves (2m x 4n), wave tile 64x64, acc[4][4].
// LDS 24 KB. CVT_A: A is fp32 row-major (cvt in stage). else: A is fp16 tiled
// [mtile][ks][4][128][8] staged via pure global_load_lds.

template<bool CVT_A>
__global__ __launch_bounds__(512) void k_gemm16(const float* __restrict__ A32,
                                                const _Float16* __restrict__ At,
                                                const _Float16* __restrict__ Wt,
                                                _Float16* __restrict__ C16,
                                                int M, int K) {
    __shared__ f16x8 AlsG[4 * 128];  //  8,192 B [g][row]
    __shared__ f16x8 BlsG[4 * 256];  // 16,384 B [g][col]

    const int m0 = blockIdx.x * 128;
    const int tid = threadIdx.x;
    const int wave = tid >> 6;
    const int lane = tid & 63;
    const int wm = wave >> 2;      // 0..1
    const int wn = wave & 3;       // 0..3

    f32x4 acc[4][4] = {};

    const int nsteps = K >> 5;

    for (int ks = 0; ks < nsteps; ++ks) {
        // ---- stage A
        if (CVT_A) {
            int row = tid >> 2;          // 0..127
            int j   = tid & 3;           // granule
            int gm = m0 + row;
            float4 v0 = make_float4(0, 0, 0, 0), v1 = v0;
            if (gm < M) {
                const float* ap = A32 + (size_t)gm * K + ks * 32 + j * 8;
                v0 = *(const float4*)ap;
                v1 = *(const float4*)(ap + 4);
            }
            f16x8 w;
            w[0] = (_Float16)v0.x; w[1] = (_Float16)v0.y;
            w[2] = (_Float16)v0.z; w[3] = (_Float16)v0.w;
            w[4] = (_Float16)v1.x; w[5] = (_Float16)v1.y;
            w[6] = (_Float16)v1.z; w[7] = (_Float16)v1.w;
            AlsG[j * 128 + row] = w;
        } else {
            const char* asrc = (const char*)(At + ((size_t)blockIdx.x * nsteps + ks) * A_STEP_SHORTS);
            int byteoff = tid * 16;      // 512*16 = 8192 B
            __builtin_amdgcn_global_load_lds(GLBP(asrc + byteoff),
                                             LDSP((char*)AlsG + byteoff), 16, 0, 0);
        }
        // ---- stage B: 16 KB = 1024 x 16B, 2 chunks/thread
        {
            const char* bsrc = (const char*)(Wt + (size_t)ks * B_STEP_SHORTS);
#pragma unroll
            for (int c = 0; c < 2; ++c) {
                int byteoff = (c * 512 + tid) * 16;
                __builtin_amdgcn_global_load_lds(GLBP(bsrc + byteoff),
                                                 LDSP((char*)BlsG + byteoff), 16, 0, 0);
            }
        }
        __syncthreads();

        {
            int g = lane >> 4;
            f16x8 af[4], bf[4];
#pragma unroll
            for (int mf = 0; mf < 4; ++mf) {
                int row = wm * 64 + mf * 16 + (lane & 15);
                af[mf] = AlsG[g * 128 + row];
            }
#pragma unroll
            for (int nf = 0; nf < 4; ++nf) {
                int col = wn * 64 + nf * 16 + (lane & 15);
                bf[nf] = BlsG[g * 256 + col];
            }
#pragma unroll
            for (int mf = 0; mf < 4; ++mf)
#pragma unroll
                for (int nf = 0; nf < 4; ++nf)
                    acc[mf][nf] = __builtin_amdgcn_mfma_f32_16x16x32_f16(af[mf], bf[nf],
                                                                         acc[mf][nf], 0, 0, 0);
        }
        __syncthreads();
    }

    // ---- epilogue: C/D layout col=lane&15, row=(lane>>4)*4+r
#pragma unroll
    for (int mf = 0; mf < 4; ++mf) {
        int row0 = m0 + wm * 64 + mf * 16 + (lane >> 4) * 4;
#pragma unroll
        for (int r = 0; r < 4; ++r) {
            int gr = row0 + r;
            if (gr < M) {
#pragma unroll
                for (int nf = 0; nf < 4; ++nf) {
                    int col = wn * 64 + nf * 16 + (lane & 15);
                    C16[(size_t)gr * HID + col] = (_Float16)acc[mf][nf][r];
                }
            }
        }
    }
}

// ---------------- gather aggregate: one wave per dst node, fp16 h, fp32 acc ----------------
// !READOUT: writes relu(agg) as fp16 into GEMM-tiled layout (aggT).
// READOUT:  emits out[d] = bout + dot(relu(agg_row), wout)

template<bool READOUT>
__global__ __launch_bounds__(256) void k_aggregate(const _Float16* __restrict__ h,
                                                   const float* __restrict__ dinv,
                                                   const int* __restrict__ rowptr,
                                                   const int2* __restrict__ erec,
                                                   const float* __restrict__ bias,
                                                   _Float16* __restrict__ aggT,
                                                   const float* __restrict__ wout,
                                                   const float* __restrict__ bout,
                                                   float* __restrict__ out,
                                                   int n) {
    int node = blockIdx.x * 4 + (threadIdx.x >> 6);
    if (node >= n) return;
    int lane = threadIdx.x & 63;

    float dd = dinv[node];
    float4 acc;
    {
        float w = dd * dd;
        f16x4 v = *(const f16x4*)(h + (size_t)node * HID + lane * 4);
        float4 b = *(const float4*)(bias + lane * 4);
        acc = make_float4(b.x + (float)v[0] * w, b.y + (float)v[1] * w,
                          b.z + (float)v[2] * w, b.w + (float)v[3] * w);
    }

    int e = rowptr[node];
    int e_end = rowptr[node + 1];
    for (; e + 1 < e_end; e += 2) {
        int2 r0 = erec[e];
        int2 r1 = erec[e + 1];
        float w0 = __int_as_float(r0.y);
        float w1 = __int_as_float(r1.y);
        f16x4 v0 = *(const f16x4*)(h + (size_t)r0.x * HID + lane * 4);
        f16x4 v1 = *(const f16x4*)(h + (size_t)r1.x * HID + lane * 4);
        acc.x += (float)v0[0] * w0 + (float)v1[0] * w1;
        acc.y += (float)v0[1] * w0 + (float)v1[1] * w1;
        acc.z += (float)v0[2] * w0 + (float)v1[2] * w1;
        acc.w += (float)v0[3] * w0 + (float)v1[3] * w1;
    }
    if (e < e_end) {
        int2 r0 = erec[e];
        float w0 = __int_as_float(r0.y);
        f16x4 v0 = *(const f16x4*)(h + (size_t)r0.x * HID + lane * 4);
        acc.x += (float)v0[0] * w0; acc.y += (float)v0[1] * w0;
        acc.z += (float)v0[2] * w0; acc.w += (float)v0[3] * w0;
    }

    if (!READOUT) {
        // relu + fp16 + tiled write: ch0 = 4*lane -> ks=lane>>3, g=(lane>>1)&3, off=(lane&1)*4
        int t = node >> 7, r = node & 127;
        int ks = lane >> 3, g = (lane >> 1) & 3, off = (lane & 1) * 4;
        f16x4 o;
        o[0] = (_Float16)fmaxf(acc.x, 0.f);
        o[1] = (_Float16)fmaxf(acc.y, 0.f);
        o[2] = (_Float16)fmaxf(acc.z, 0.f);
        o[3] = (_Float16)fmaxf(acc.w, 0.f);
        _Float16* dst = aggT + (size_t)t * AGGT_TILE_SHORTS + (((ks * 4 + g) * 128 + r) * 8 + off);
        *(f16x4*)dst = o;
    } else {
        float4 w = *(const float4*)(wout + lane * 4);
        acc.x = fmaxf(acc.x, 0.f); acc.y = fmaxf(acc.y, 0.f);
        acc.z = fmaxf(acc.z, 0.f); acc.w = fmaxf(acc.w, 0.f);
        float s = acc.x * w.x + acc.y * w.y + acc.z * w.z + acc.w * w.w;
#pragma unroll
        for (int off2 = 32; off2 > 0; off2 >>= 1) s += __shfl_down(s, off2, 64);
        if (lane == 0) out[node] = s + bout[0];
    }
}

// ---------------- launch ----------------

extern "C" void kernel_launch(void* const* d_in, const int* in_sizes, int n_in,
                              void* d_out, int out_size, void* d_ws, size_t ws_size,
                              hipStream_t stream) {
    const float* x    = (const float*)d_in[0];
    const int*   ei   = (const int*)d_in[1];
    const float* W0   = (const float*)d_in[2];
    const float* b0   = (const float*)d_in[3];
    const float* W1   = (const float*)d_in[4];
    const float* b1   = (const float*)d_in[5];
    const float* W2   = (const float*)d_in[6];
    const float* b2   = (const float*)d_in[7];
    const float* Wout = (const float*)d_in[8];
    const float* bout = (const float*)d_in[9];
    float* out = (float*)d_out;

    const int n = in_sizes[0] / IN_CH;   // 50000
    const int E = in_sizes[1] / 2;       // 800000
    const int* src = ei;
    const int* dst = ei + E;

    const int mtiles = (n + 127) / 128;  // 391

    // workspace carve-up
    float* dinv   = (float*)d_ws;                        // NPAD
    int*   rowptr = (int*)(dinv + NPAD);                 // NPAD
    int*   cursor = rowptr + NPAD;                       // NPAD
    int2*  erec   = (int2*)(cursor + NPAD);              // E
    int*   bsum   = (int*)(erec + 800000);               // 64
    int*   boff   = bsum + 64;                           // 64
    _Float16* Wt0 = (_Float16*)(boff + 64);              // 512*256
    _Float16* Wt1 = Wt0 + IN_CH * HID;                   // 256*256
    _Float16* Wt2 = Wt1 + HID * HID;                     // 256*256
    _Float16* h16 = Wt2 + HID * HID;                     // n*HID row-major
    _Float16* aggT = h16 + (size_t)NPAD * HID;           // mtiles*32768 tiled

    const int nb_e = (E + 255) / 256;
    const int nb_scan = (n + 1023) / 1024;

    // ---- CSR build ----
    hipMemsetAsync(cursor, 0, (size_t)n * 4, stream);
    k_count<<<nb_e, 256, 0, stream>>>(dst, cursor, E);
    k_scan_bsum<<<nb_scan, 256, 0, stream>>>(cursor, bsum, n);
    k_scan_boff<<<1, 64, 0, stream>>>(bsum, boff, nb_scan);
    k_scan_write<<<nb_scan, 256, 0, stream>>>(cursor, boff, rowptr, dinv, n);
    hipMemsetAsync(cursor, 0, (size_t)n * 4, stream);
    k_fill<<<nb_e, 256, 0, stream>>>(src, dst, rowptr, cursor, dinv, erec, E);

    // ---- weight convert (one launch) ----
    k_wcvt3<<<(IN_CH * HID + 2 * HID * HID) / 256, 256, 0, stream>>>(W0, W1, W2, Wt0, Wt1, Wt2);

    const int agg_blocks = (n + 3) / 4;

    // layer 0: h = x @ W0 (fp32->fp16 cvt in stage)
    k_gemm16<true><<<mtiles, 512, 0, stream>>>(x, nullptr, Wt0, h16, n, IN_CH);
    k_aggregate<false><<<agg_blocks, 256, 0, stream>>>(h16, dinv, rowptr, erec, b0,
                                                       aggT, nullptr, nullptr, nullptr, n);
    // layer 1: h = relu(agg) @ W1 (A via global_load_lds from aggT)
    k_gemm16<false><<<mtiles, 512, 0, stream>>>(nullptr, aggT, Wt1, h16, n, HID);
    k_aggregate<false><<<agg_blocks, 256, 0, stream>>>(h16, dinv, rowptr, erec, b1,
                                                       aggT, nullptr, nullptr, nullptr, n);
    // layer 2: h = relu(agg) @ W2
    k_gemm16<false><<<mtiles, 512, 0, stream>>>(nullptr, aggT, Wt2, h16, n, HID);
    k_aggregate<true><<<agg_blocks, 256, 0, stream>>>(h16, dinv, rowptr, erec, b2,
                                                      nullptr, Wout, bout, out, n);
}